// Round 1
// baseline (802.682 us; speedup 1.0000x reference)
//
#include <hip/hip_runtime.h>
#include <hip/hip_bf16.h>
#include <math.h>

#define NN 100000
#define NE 1600000
#define NB_SCAN ((NN + 255) / 256)  // 391
#define NBUK 98                     // dst >> 10, 99999>>10 = 97
#define CHUNK 2048                  // edges per bucket_scatter block
#define G1_GRID 1563                // (NN+63)/64 gemm1 blocks
#define H_GRID 1563                 // ceil((NE/4)/256) hist blocks

typedef __attribute__((ext_vector_type(8))) short bf8_t;   // 8 bf16 = 4 VGPRs
typedef __attribute__((ext_vector_type(4))) float f4_t;    // 4 fp32 acc
typedef __attribute__((ext_vector_type(8))) unsigned short us8_t;  // 16B

__device__ __forceinline__ ushort f2b(float f) {
  __hip_bfloat16 h = __float2bfloat16(f);  // RNE
  return *(ushort*)&h;
}
__device__ __forceinline__ float b2f(ushort u) {
  return __uint_as_float(((unsigned)u) << 16);
}

// ---------------------------------------------------------------------------
// Fused: blocks [0,G1_GRID) run GEMM1 (bf16 MFMA, Y = bf16(X@W1));
//        blocks [G1_GRID, G1_GRID+H_GRID) run the dst-degree histogram.
// The two are independent -> concurrent occupancy instead of serial launches.
// ---------------------------------------------------------------------------
__global__ __launch_bounds__(256) void gemm1_hist_kernel(
    const float* __restrict__ X, const float* __restrict__ Wf,
    ushort* __restrict__ Y, const int* __restrict__ dst,
    int* __restrict__ deg) {
  if (blockIdx.x >= G1_GRID) {
    int idx = (blockIdx.x - G1_GRID) * 256 + threadIdx.x;
    if (idx < NE / 4) {
      int4 d4 = ((const int4*)dst)[idx];
      atomicAdd(&deg[d4.x], 1);
      atomicAdd(&deg[d4.y], 1);
      atomicAdd(&deg[d4.z], 1);
      atomicAdd(&deg[d4.w], 1);
    }
    return;
  }
  // GEMM1: Y[M,64] = bf16( X[M,512] @ W1[512,64] ), K=512 N=64
  __shared__ ushort xs[64][72];
  __shared__ ushort wsh[64][72];
  const int tid = threadIdx.x;
  const int wave = tid >> 6;
  const int lane = tid & 63;
  const int row0 = blockIdx.x * 64;

  f4_t acc[4];
#pragma unroll
  for (int t = 0; t < 4; t++) acc[t] = (f4_t){0.f, 0.f, 0.f, 0.f};

  for (int k0 = 0; k0 < 512; k0 += 64) {
#pragma unroll
    for (int i = 0; i < 4; i++) {
      int fidx = i * 256 + tid;
      int row = fidx >> 4;
      int kq = (fidx & 15) * 4;
      ushort4 uv = make_ushort4(0, 0, 0, 0);
      if (row0 + row < NN) {
        float4 xv = *(const float4*)&X[(long)(row0 + row) * 512 + k0 + kq];
        uv = make_ushort4(f2b(xv.x), f2b(xv.y), f2b(xv.z), f2b(xv.w));
      }
      *(ushort4*)&xs[row][kq] = uv;
    }
#pragma unroll
    for (int i = 0; i < 4; i++) {
      int widx = i * 256 + tid;
      int n = widx & 63;
      int kq = (widx >> 6) * 4;
      ushort4 uv;
      uv.x = f2b(Wf[(long)(k0 + kq + 0) * 64 + n]);
      uv.y = f2b(Wf[(long)(k0 + kq + 1) * 64 + n]);
      uv.z = f2b(Wf[(long)(k0 + kq + 2) * 64 + n]);
      uv.w = f2b(Wf[(long)(k0 + kq + 3) * 64 + n]);
      *(ushort4*)&wsh[n][kq] = uv;
    }
    __syncthreads();
#pragma unroll
    for (int s = 0; s < 2; s++) {
      bf8_t af = *(const bf8_t*)&xs[wave * 16 + (lane & 15)][s * 32 + (lane >> 4) * 8];
#pragma unroll
      for (int t = 0; t < 4; t++) {
        bf8_t bf = *(const bf8_t*)&wsh[t * 16 + (lane & 15)][s * 32 + (lane >> 4) * 8];
        acc[t] = __builtin_amdgcn_mfma_f32_16x16x32_bf16(af, bf, acc[t], 0, 0, 0);
      }
    }
    __syncthreads();
  }
  const int crow0 = row0 + wave * 16 + (lane >> 4) * 4;
  const int ccol = lane & 15;
#pragma unroll
  for (int t = 0; t < 4; t++) {
    int col = ccol + t * 16;
#pragma unroll
    for (int r = 0; r < 4; r++) {
      int row = crow0 + r;
      if (row < NN) Y[(long)row * 64 + col] = f2b(acc[t][r]);
    }
  }
}

// ---------------------------------------------------------------------------
// CSR build: scan -> bucket scatter -> fine fill (hist fused above)
// ---------------------------------------------------------------------------
__global__ __launch_bounds__(256) void scan_blocks_kernel(
    const int* __restrict__ deg, int* __restrict__ rowptr,
    int* __restrict__ partials, int n) {
  __shared__ int tmp[256];
  int tid = threadIdx.x;
  int gid = blockIdx.x * 256 + tid;
  int v = (gid < n) ? deg[gid] : 0;
  tmp[tid] = v;
  __syncthreads();
#pragma unroll
  for (int off = 1; off < 256; off <<= 1) {
    int t = (tid >= off) ? tmp[tid - off] : 0;
    __syncthreads();
    tmp[tid] += t;
    __syncthreads();
  }
  if (gid < n) rowptr[gid] = tmp[tid] - v;
  if (tid == 255) partials[blockIdx.x] = tmp[255];
}

// scan partials; then bcur[b] = scanned partials[4b] (== rowptr[b<<10],
// since (b<<10)%256==0 makes the local exclusive prefix zero there).
__global__ __launch_bounds__(64) void scan_partials_bcur_kernel(
    int* __restrict__ p, int n, int* __restrict__ bcur) {
  int lane = threadIdx.x;
  int carry = 0;
  for (int base = 0; base < n; base += 64) {
    int i = base + lane;
    int v = (i < n) ? p[i] : 0;
#pragma unroll
    for (int off = 1; off < 64; off <<= 1) {
      int t = __shfl_up(v, off, 64);
      if (lane >= off) v += t;
    }
    int total = __shfl(v, 63, 64);
    int ex = __shfl_up(v, 1, 64);
    if (lane == 0) ex = 0;
    if (i < n) p[i] = carry + ex;
    carry += total;
  }
  __threadfence_block();
  __syncthreads();
  for (int b = lane; b < NBUK; b += 64) bcur[b] = p[4 * b];
}

__global__ __launch_bounds__(256) void add_offsets_kernel(
    int* __restrict__ rowptr, int* __restrict__ cursor,
    const int* __restrict__ partials, int n) {
  int gid = blockIdx.x * 256 + threadIdx.x;
  if (gid < n) {
    int v = rowptr[gid] + partials[blockIdx.x];
    rowptr[gid] = v;
    cursor[gid] = v;
  }
}

// Pass B: group edges by bucket (dst>>10) with block-aggregated reservation.
__global__ __launch_bounds__(256) void bucket_scatter_kernel(
    const int* __restrict__ src, const int* __restrict__ dst,
    const float* __restrict__ ew, int* __restrict__ bcur,
    int2* __restrict__ esw, int* __restrict__ ed, int n) {
  __shared__ int lcnt[NBUK];
  __shared__ int lbase[NBUK];
  const int tid = threadIdx.x;
  const int e0 = blockIdx.x * CHUNK;
  for (int i = tid; i < NBUK; i += 256) lcnt[i] = 0;
  __syncthreads();

  int es[8], ds[8], rk[8];
  float wv[8];
#pragma unroll
  for (int k = 0; k < 8; k++) {
    int e = e0 + k * 256 + tid;
    if (e < n) {
      es[k] = src[e];
      ds[k] = dst[e];
      wv[k] = ew[e];
      rk[k] = atomicAdd(&lcnt[ds[k] >> 10], 1);
    } else {
      ds[k] = -1;
    }
  }
  __syncthreads();
  for (int i = tid; i < NBUK; i += 256)
    lbase[i] = lcnt[i] ? atomicAdd(&bcur[i], lcnt[i]) : 0;
  __syncthreads();
#pragma unroll
  for (int k = 0; k < 8; k++) {
    if (ds[k] >= 0) {
      int p = lbase[ds[k] >> 10] + rk[k];
      esw[p] = make_int2(es[k], __float_as_int(wv[k]));
      ed[p] = ds[k];
    }
  }
}

// Pass C: per-node scatter stays inside one bucket's <=132KB CSR window.
__global__ __launch_bounds__(256) void fine_fill_kernel(
    const int2* __restrict__ esw, const int* __restrict__ ed,
    int* __restrict__ cursor, int2* __restrict__ csr, int n) {
  int i = blockIdx.x * 256 + threadIdx.x;
  if (i < n) {
    int d = ed[i];
    int pos = atomicAdd(&cursor[d], 1);
    csr[pos] = esw[i];
  }
}

// ---------------------------------------------------------------------------
// Fused aggregation + next-layer GEMM (D_in=64 -> NOUT):
//   row  = sum_{e in row} w_e * H[src_e]          (gather, D=64 bf16)
//   t    = relu(row + b_in)                       (fp32)
//   out  = bf16( t @ W )                          (per-row matvec, W in LDS)
// 8 rows per wave, 4 waves/block -> 32 rows/block; W staged fp32 once/block.
// ---------------------------------------------------------------------------
template <int NOUT>
__global__ __launch_bounds__(256) void agg_mm_kernel(
    const int* __restrict__ rowptr, const int* __restrict__ deg,
    const int2* __restrict__ csr, const ushort* __restrict__ H,
    const float* __restrict__ bin, const float* __restrict__ Wf,
    ushort* __restrict__ out, int nR) {
  __shared__ float Wsh[64 * NOUT];
  const int tid = threadIdx.x;
#pragma unroll
  for (int i = 0; i < (64 * NOUT + 255) / 256; i++) {
    int idx = i * 256 + tid;
    if (idx < 64 * NOUT) Wsh[idx] = Wf[idx];
  }
  const int lane = tid & 63;
  const int wave = tid >> 6;
  const int g = lane >> 3;
  const int sub = lane & 7;
  const int cn = (lane < NOUT) ? lane : 0;  // lanes>=NOUT read col0 (broadcast)
  float bk[8];
#pragma unroll
  for (int k = 0; k < 8; k++) bk[k] = bin[sub * 8 + k];
  __syncthreads();

  const int rbase = blockIdx.x * 32 + wave * 8;
  for (int i = 0; i < 8; i++) {
    const int r = rbase + i;
    if (r >= nR) return;
    const int beg = rowptr[r];
    const int d = deg[r];
    float acc[8];
#pragma unroll
    for (int k = 0; k < 8; k++) acc[k] = 0.f;
    for (int j0 = 0; j0 < d; j0 += 8) {
      int jj = j0 + g;
      int2 cw = (jj < d) ? csr[beg + jj] : make_int2(0, 0);  // w=0 pad
      float w = __int_as_float(cw.y);
      us8_t hv = *(const us8_t*)&H[(long)cw.x * 64 + sub * 8];
#pragma unroll
      for (int k = 0; k < 8; k++) acc[k] += w * b2f(hv[k]);
    }
#pragma unroll
    for (int off = 8; off < 64; off <<= 1)
#pragma unroll
      for (int k = 0; k < 8; k++) acc[k] += __shfl_xor(acc[k], off, 64);
    // all 64 lanes now hold the full row: lane(sub) has row[sub*8+k]
    float tv[8];
#pragma unroll
    for (int k = 0; k < 8; k++) tv[k] = fmaxf(acc[k] + bk[k], 0.f);
    float o = 0.f;
#pragma unroll
    for (int m = 0; m < 64; m++) {
      float rv = __shfl(tv[m & 7], m >> 3, 8);  // broadcast row[m] within 8-lane grp
      o = fmaf(rv, Wsh[m * NOUT + cn], o);
    }
    if (lane < NOUT) out[(long)r * NOUT + lane] = f2b(o);
  }
}

// ---------------------------------------------------------------------------
// Layer-3 fused: chunked aggregation (D=40) + bias + log_softmax, fp32 out.
// ---------------------------------------------------------------------------
__global__ __launch_bounds__(256) void agg_lsm_kernel(
    const int* __restrict__ rowptr, const int* __restrict__ deg,
    const int2* __restrict__ csr, const ushort* __restrict__ H,
    const float* __restrict__ b, float* __restrict__ out, int nR) {
  int lane = threadIdx.x & 63;
  int r = blockIdx.x * 4 + (threadIdx.x >> 6);
  if (r >= nR) return;
  int beg = rowptr[r];
  int d = deg[r];
  int g = lane >> 3;
  int sub = lane & 7;
  float acc[8];
#pragma unroll
  for (int k = 0; k < 8; k++) acc[k] = 0.f;

  for (int j0 = 0; j0 < d; j0 += 8) {
    int jj = j0 + g;
    int2 cw = (jj < d) ? csr[beg + jj] : make_int2(0, 0);
    float w = __int_as_float(cw.y);
    if (sub < 5) {
      us8_t hv = *(const us8_t*)&H[(long)cw.x * 40 + sub * 8];
#pragma unroll
      for (int k = 0; k < 8; k++) acc[k] += w * b2f(hv[k]);
    }
  }
#pragma unroll
  for (int off = 8; off < 64; off <<= 1)
#pragma unroll
    for (int k = 0; k < 8; k++) acc[k] += __shfl_xor(acc[k], off, 64);

  float v[8];
  float m = -INFINITY, s = 0.f;
  if (sub < 5) {
#pragma unroll
    for (int k = 0; k < 8; k++) {
      v[k] = acc[k] + b[sub * 8 + k];
      m = fmaxf(m, v[k]);
    }
  }
#pragma unroll
  for (int off = 1; off < 8; off <<= 1) m = fmaxf(m, __shfl_xor(m, off, 64));
  if (sub < 5) {
#pragma unroll
    for (int k = 0; k < 8; k++) s += __expf(v[k] - m);
  }
#pragma unroll
  for (int off = 1; off < 8; off <<= 1) s += __shfl_xor(s, off, 64);

  if (g == 0 && sub < 5) {
    float lg = m + __logf(s);
    float4 o0 = make_float4(v[0] - lg, v[1] - lg, v[2] - lg, v[3] - lg);
    float4 o1 = make_float4(v[4] - lg, v[5] - lg, v[6] - lg, v[7] - lg);
    *(float4*)&out[(long)r * 40 + sub * 8] = o0;
    *(float4*)&out[(long)r * 40 + sub * 8 + 4] = o1;
  }
}

extern "C" void kernel_launch(void* const* d_in, const int* in_sizes, int n_in,
                              void* d_out, int out_size, void* d_ws,
                              size_t ws_size, hipStream_t stream) {
  const int* edge_index = (const int*)d_in[0];
  const float* features = (const float*)d_in[1];
  const float* ew = (const float*)d_in[2];
  const float* W1 = (const float*)d_in[3];
  const float* b1 = (const float*)d_in[4];
  const float* W2 = (const float*)d_in[5];
  const float* b2 = (const float*)d_in[6];
  const float* W3 = (const float*)d_in[7];
  const float* b3 = (const float*)d_in[8];
  float* out = (float*)d_out;
  const int* src = edge_index;
  const int* dst = edge_index + NE;

  // workspace layout (no aliasing: GEMM1 now overlaps the CSR build)
  char* p = (char*)d_ws;
  int2* csr = (int2*)p;              p += (size_t)NE * 8;       // 12.8 MB
  int2* esw = (int2*)p;              p += (size_t)NE * 8;       // 12.8 MB
  int* ed = (int*)p;                 p += (size_t)NE * 4;       // 6.4 MB
  int* deg = (int*)p;                p += (size_t)NN * 4;
  int* rowptr = (int*)p;             p += (size_t)NN * 4;
  int* cursor = (int*)p;             p += (size_t)NN * 4;
  int* partials = (int*)p;           p += 1024 * 4;
  int* bcur = (int*)p;               p += 128 * 4;
  ushort* hb = (ushort*)p;           p += (size_t)NN * 64 * 2;  // layer buffers
  ushort* xb = (ushort*)p;           p += (size_t)NN * 64 * 2;

  dim3 blk(256);
  const int edge_grid = (NE + 255) / 256;
  const int agg_grid = (NN + 31) / 32;
  const int row_grid = (NN + 3) / 4;

  // ---- CSR build (by dst), GEMM1 fused into the histogram launch ----
  hipMemsetAsync(deg, 0, NN * sizeof(int), stream);
  gemm1_hist_kernel<<<G1_GRID + H_GRID, blk, 0, stream>>>(features, W1, hb,
                                                          dst, deg);
  scan_blocks_kernel<<<NB_SCAN, blk, 0, stream>>>(deg, rowptr, partials, NN);
  scan_partials_bcur_kernel<<<1, 64, 0, stream>>>(partials, NB_SCAN, bcur);
  add_offsets_kernel<<<NB_SCAN, blk, 0, stream>>>(rowptr, cursor, partials, NN);
  bucket_scatter_kernel<<<(NE + CHUNK - 1) / CHUNK, blk, 0, stream>>>(
      src, dst, ew, bcur, esw, ed, NE);
  fine_fill_kernel<<<edge_grid, blk, 0, stream>>>(esw, ed, cursor, csr, NE);

  // ---- layer 1 agg + layer 2 GEMM fused ----
  agg_mm_kernel<64><<<agg_grid, blk, 0, stream>>>(rowptr, deg, csr, hb, b1,
                                                  W2, xb, NN);
  // ---- layer 2 agg + layer 3 GEMM fused ----
  agg_mm_kernel<40><<<agg_grid, blk, 0, stream>>>(rowptr, deg, csr, xb, b2,
                                                  W3, hb, NN);
  // ---- layer 3 agg + bias + log_softmax ----
  agg_lsm_kernel<<<row_grid, blk, 0, stream>>>(rowptr, deg, csr, hb, b3, out,
                                               NN);
}